// Round 13
// baseline (151.013 us; speedup 1.0000x reference)
//
#include <hip/hip_runtime.h>
#include <hip/hip_cooperative_groups.h>

namespace cg = cooperative_groups;

#define HID 128
#define NBLK 64          // partition blocks (cooperative grid)
#define PTHREADS 1024    // threads per partition block
#define MAXBUCK 2048     // buckets of 32 dst nodes; supports n <= 65536
#define CAP 3072         // LDS capacity (edges) per bucket in bucket_gather

typedef unsigned short ushort_t;
typedef unsigned int uint_t;
typedef short bf16x8 __attribute__((ext_vector_type(8)));
typedef float f32x4 __attribute__((ext_vector_type(4)));

__device__ __forceinline__ float bflo(uint_t u) { return __uint_as_float(u << 16); }
__device__ __forceinline__ float bfhi(uint_t u) { return __uint_as_float(u & 0xFFFF0000u); }
__device__ __forceinline__ uint_t f2bf(float f) {
    uint_t x = __float_as_uint(f);
    return (x + 0x7FFFu + ((x >> 16) & 1u)) >> 16;   // RNE
}

__device__ __forceinline__ int load_idx(const int* __restrict__ E, int pos, bool is64) {
    return is64 ? E[2 * pos] : E[pos];
}

// ---------------------------------------------------------------------------
// prep_all: blocks 0..127 transpose W1/W2 to bf16 Wt[col][k]; block 128
// detects int64 vs int32 edge_index layout (for the fallback path only).
// ---------------------------------------------------------------------------
__global__ __launch_bounds__(256) void prep_all(
    const int* __restrict__ E, int* __restrict__ flag,
    const float* __restrict__ W1, const float* __restrict__ W2,
    ushort_t* __restrict__ wt1, ushort_t* __restrict__ wt2)
{
    if (blockIdx.x == 128) {
        if (threadIdx.x < 64) {
            const int l = threadIdx.x;
            const int v = E[2 * l + 1] | E[2 * (l + 64) + 1];
            unsigned long long b = __ballot(v != 0);
            if (l == 0) flag[0] = (b == 0ull) ? 1 : 0;
        }
        return;
    }
    const int id = blockIdx.x * 256 + threadIdx.x;       // 0..32767
    const float* W = (id < 16384) ? W1 : W2;
    ushort_t* O    = (id < 16384) ? wt1 : wt2;
    const int i   = id & 16383;
    const int col = i >> 7;
    const int k   = i & 127;
    O[col * 128 + k] = (ushort_t)f2bf(W[k * 128 + col]);
}

// ---------------------------------------------------------------------------
// MFMA GEMM: T = relu(X @ W + B) using v_mfma_f32_16x16x32_bf16.
// Block = 256 thr = 4 waves; each wave owns 16 rows x 128 cols.
// Wt (transposed bf16 W) staged once into LDS with granule-XOR swizzle.
// No per-K barriers: LDS is read-only after the single stage barrier.
// C/D layout (verified): col=lane&15, row=(lane>>4)*4+reg.
// mode 0: write T rows (bf16). mode 1: fuse dot with Wf, write scalar S.
// ---------------------------------------------------------------------------
__global__ __launch_bounds__(256) void mlp_mfma(
    const float* __restrict__ X, const ushort_t* __restrict__ Wt,
    const float* __restrict__ Bv, const float* __restrict__ Wf,
    ushort_t* __restrict__ T, float* __restrict__ S, int n, int mode)
{
    __shared__ ushort_t Wl[HID * HID];   // 32 KB, swizzled

    {
        const uint4* src = (const uint4*)Wt;
        for (int o = threadIdx.x; o < 2048; o += 256) {
            const uint4 v = src[o];
            const int col = o >> 4;
            const int g   = o & 15;
            const int gs  = g ^ (col & 7);
            *(uint4*)(Wl + col * HID + gs * 8) = v;
        }
    }
    __syncthreads();

    const int l  = threadIdx.x & 63;
    const int wv = threadIdx.x >> 6;
    const int rowbase = blockIdx.x * 64 + wv * 16;
    const int lr = l & 15;               // A-row / B-col / C-col lane index
    const int lg = l >> 4;               // k-group / C-row group

    f32x4 acc[8];
#pragma unroll
    for (int ct = 0; ct < 8; ++ct) acc[ct] = (f32x4){0.f, 0.f, 0.f, 0.f};

    const int arow = rowbase + lr;
    const bool rok = (arow < n);

    for (int kk = 0; kk < 4; ++kk) {
        bf16x8 a;
        if (rok) {
            const float* xp = X + (size_t)arow * HID + kk * 32 + lg * 8;
            const float4 x0 = *(const float4*)xp;
            const float4 x1 = *(const float4*)(xp + 4);
            a[0] = (short)f2bf(x0.x); a[1] = (short)f2bf(x0.y);
            a[2] = (short)f2bf(x0.z); a[3] = (short)f2bf(x0.w);
            a[4] = (short)f2bf(x1.x); a[5] = (short)f2bf(x1.y);
            a[6] = (short)f2bf(x1.z); a[7] = (short)f2bf(x1.w);
        } else {
            a = (bf16x8){0, 0, 0, 0, 0, 0, 0, 0};
        }
#pragma unroll
        for (int ct = 0; ct < 8; ++ct) {
            const int col = ct * 16 + lr;
            const int g   = kk * 4 + lg;
            const int gs  = g ^ (col & 7);
            const bf16x8 b = *(const bf16x8*)(Wl + col * HID + gs * 8);
            acc[ct] = __builtin_amdgcn_mfma_f32_16x16x32_bf16(a, b, acc[ct], 0, 0, 0);
        }
    }

    if (mode == 0) {
#pragma unroll
        for (int ct = 0; ct < 8; ++ct) {
            const float bvc = Bv[ct * 16 + lr];
#pragma unroll
            for (int i = 0; i < 4; ++i) {
                const int r = rowbase + lg * 4 + i;
                if (r < n) {
                    const float v = fmaxf(acc[ct][i] + bvc, 0.f);
                    T[(size_t)r * HID + ct * 16 + lr] = (ushort_t)f2bf(v);
                }
            }
        }
    } else {
        float p0 = 0.f, p1 = 0.f, p2 = 0.f, p3 = 0.f;
#pragma unroll
        for (int ct = 0; ct < 8; ++ct) {
            const float bvc = Bv[ct * 16 + lr];
            const float wfc = Wf[ct * 16 + lr];
            p0 += fmaxf(acc[ct][0] + bvc, 0.f) * wfc;
            p1 += fmaxf(acc[ct][1] + bvc, 0.f) * wfc;
            p2 += fmaxf(acc[ct][2] + bvc, 0.f) * wfc;
            p3 += fmaxf(acc[ct][3] + bvc, 0.f) * wfc;
        }
#pragma unroll
        for (int m = 1; m <= 8; m <<= 1) {
            p0 += __shfl_xor(p0, m);
            p1 += __shfl_xor(p1, m);
            p2 += __shfl_xor(p2, m);
            p3 += __shfl_xor(p3, m);
        }
        if (lr == 0) {
            const int r = rowbase + lg * 4;
            if (r + 0 < n) S[r + 0] = p0;
            if (r + 1 < n) S[r + 1] = p1;
            if (r + 2 < n) S[r + 2] = p2;
            if (r + 3 < n) S[r + 3] = p3;
        }
    }
}

// ---------------------------------------------------------------------------
// Cooperative partition: hist -> scan -> scatter in ONE launch (3 grid syncs).
// NBLK blocks x PTHREADS. m = nbuck*NBLK counters; each block scans exactly
// nbuck of them (m divisible by NBLK by construction). is64 detected locally.
// Output: pe[] packed (src | dlow<<16) grouped by bucket, basea[] boundaries.
// ---------------------------------------------------------------------------
__global__ __launch_bounds__(PTHREADS) void coop_partition(
    const int* __restrict__ E, int* __restrict__ histT,
    int* __restrict__ basea, int* __restrict__ bsum, uint_t* __restrict__ pe,
    int n_edges, int n_nodes, int nbuck)
{
    cg::grid_group grid = cg::this_grid();
    __shared__ int h[MAXBUCK];
    __shared__ int sd[PTHREADS];
    __shared__ int s_is64;

    const int t = threadIdx.x;
    if (t < 64) {
        const int v = E[2 * t + 1] | E[2 * (t + 64) + 1];
        unsigned long long b = __ballot(v != 0);
        if (t == 0) s_is64 = (b == 0ull) ? 1 : 0;
    }
    for (int i = t; i < nbuck; i += PTHREADS) h[i] = 0;
    __syncthreads();
    const bool is64 = (s_is64 != 0);

    const int chunk = (n_edges + NBLK - 1) / NBLK;
    const int c0 = blockIdx.x * chunk;
    const int c1 = min(c0 + chunk, n_edges);

    // ---- phase 1: histogram (count only edges valid on BOTH ends) ----
    for (int e = c0 + t; e < c1; e += PTHREADS) {
        const int src = load_idx(E, e, is64);
        const int dst = load_idx(E, n_edges + e, is64);
        if ((unsigned)src < (unsigned)n_nodes && (unsigned)dst < (unsigned)n_nodes)
            atomicAdd(&h[dst >> 5], 1);
    }
    __syncthreads();
    for (int i = t; i < nbuck; i += PTHREADS)
        histT[i * NBLK + blockIdx.x] = h[i];
    grid.sync();

    // ---- phase 2a: per-block exclusive scan of its nbuck-element chunk ----
    {
        const int base0 = blockIdx.x * nbuck;
        const int i0 = t * 2, i1 = t * 2 + 1;
        const int v0 = (i0 < nbuck) ? histT[base0 + i0] : 0;
        const int v1 = (i1 < nbuck) ? histT[base0 + i1] : 0;
        const int ps = v0 + v1;
        sd[t] = ps;
        __syncthreads();
        for (int d = 1; d < PTHREADS; d <<= 1) {
            const int u = (t >= d) ? sd[t - d] : 0;
            __syncthreads();
            sd[t] += u;
            __syncthreads();
        }
        const int excl = sd[t] - ps;
        if (i0 < nbuck) basea[base0 + i0] = excl;
        if (i1 < nbuck) basea[base0 + i1] = excl + v0;
        if (t == PTHREADS - 1) bsum[blockIdx.x] = sd[PTHREADS - 1];
    }
    grid.sync();

    // ---- phase 2b: block 0 wave-scans the NBLK block sums ----
    if (blockIdx.x == 0 && t < 64) {
        const int v = (t < NBLK) ? bsum[t] : 0;
        int s = v;
        for (int d = 1; d < 64; d <<= 1) {
            const int u = __shfl_up(s, d, 64);
            if (t >= d) s += u;
        }
        if (t < NBLK) bsum[t] = s - v;              // exclusive block base
        if (t == 63) basea[nbuck * NBLK] = s;       // grand total
    }
    grid.sync();

    // ---- phase 2c: add block base ----
    {
        const int base0 = blockIdx.x * nbuck;
        const int add = bsum[blockIdx.x];
        for (int i = t; i < nbuck; i += PTHREADS) basea[base0 + i] += add;
    }
    grid.sync();

    // ---- phase 3: scatter into per-(block,bucket) exclusive ranges ----
    for (int i = t; i < nbuck; i += PTHREADS)
        h[i] = basea[i * NBLK + blockIdx.x];
    __syncthreads();
    for (int e = c0 + t; e < c1; e += PTHREADS) {
        const int src = load_idx(E, e, is64);
        const int dst = load_idx(E, n_edges + e, is64);
        if ((unsigned)src >= (unsigned)n_nodes || (unsigned)dst >= (unsigned)n_nodes) continue;
        const int p = atomicAdd(&h[dst >> 5], 1);
        pe[p] = (uint_t)src | ((uint_t)(dst & 31) << 16);
    }
}

// ---------------------------------------------------------------------------
// Fused bucket CSR + vector gather: one 256-thread block per bucket of 32
// dst nodes. Builds the per-dst sorted src list in LDS (count -> shfl-scan
// -> place), then 8 x 32-lane groups gather T rows via LDS-resident indices.
// ---------------------------------------------------------------------------
__global__ __launch_bounds__(256) void bucket_gather(
    const uint_t* __restrict__ pe, const int* __restrict__ basea,
    const ushort_t* __restrict__ T, float* __restrict__ H,
    int* __restrict__ ovf, int n_nodes, int nbuck)
{
    __shared__ int sid[CAP];
    __shared__ int cnt[32];
    __shared__ int cur[32];
    __shared__ int loff[32];
    const int b = blockIdx.x;
    const int t = threadIdx.x;
    const int start = basea[b * NBLK];
    const int end   = basea[(b + 1) * NBLK];
    const int m     = end - start;

    if (t < 32) cnt[t] = 0;
    __syncthreads();
    for (int i = start + t; i < end; i += 256)
        atomicAdd(&cnt[(pe[i] >> 16) & 31], 1);
    __syncthreads();
    if (t < 32) {
        const int v = cnt[t];
        int s = v;
        for (int d = 1; d < 32; d <<= 1) {
            const int u = __shfl_up(s, d, 64);
            if (t >= d) s += u;
        }
        const int excl = s - v;
        loff[t] = excl;
        cur[t]  = excl;
    }
    __syncthreads();

    const bool fits = (m <= CAP);
    for (int i = start + t; i < end; i += 256) {
        const uint_t w = pe[i];
        const int p = atomicAdd(&cur[(w >> 16) & 31], 1);
        const int s = (int)(w & 0xFFFFu);
        if (fits) sid[p] = s;
        else      ovf[start + p] = s;
    }
    __syncthreads();

    const int grp = t >> 5;
    const int l32 = t & 31;
    const int j0  = l32 * 4;
    for (int nd = grp; nd < 32; nd += 8) {
        const int node = b * 32 + nd;
        if (node >= n_nodes) break;
        const int k0 = loff[nd];
        const int k1 = (nd < 31) ? loff[nd + 1] : m;
        float4 a0 = {0.f, 0.f, 0.f, 0.f};
        float4 a1 = {0.f, 0.f, 0.f, 0.f};
        float4 a2 = {0.f, 0.f, 0.f, 0.f};
        float4 a3 = {0.f, 0.f, 0.f, 0.f};
        int k = k0;
        for (; k + 4 <= k1; k += 4) {
            const int s0 = fits ? sid[k + 0] : ovf[start + k + 0];
            const int s1 = fits ? sid[k + 1] : ovf[start + k + 1];
            const int s2 = fits ? sid[k + 2] : ovf[start + k + 2];
            const int s3 = fits ? sid[k + 3] : ovf[start + k + 3];
            const uint2 u0 = *(const uint2*)(T + (size_t)s0 * HID + j0);
            const uint2 u1 = *(const uint2*)(T + (size_t)s1 * HID + j0);
            const uint2 u2 = *(const uint2*)(T + (size_t)s2 * HID + j0);
            const uint2 u3 = *(const uint2*)(T + (size_t)s3 * HID + j0);
            a0.x += bflo(u0.x); a0.y += bfhi(u0.x);
            a0.z += bflo(u0.y); a0.w += bfhi(u0.y);
            a1.x += bflo(u1.x); a1.y += bfhi(u1.x);
            a1.z += bflo(u1.y); a1.w += bfhi(u1.y);
            a2.x += bflo(u2.x); a2.y += bfhi(u2.x);
            a2.z += bflo(u2.y); a2.w += bfhi(u2.y);
            a3.x += bflo(u3.x); a3.y += bfhi(u3.x);
            a3.z += bflo(u3.y); a3.w += bfhi(u3.y);
        }
        for (; k < k1; ++k) {
            const int s0 = fits ? sid[k] : ovf[start + k];
            const uint2 u0 = *(const uint2*)(T + (size_t)s0 * HID + j0);
            a0.x += bflo(u0.x); a0.y += bfhi(u0.x);
            a0.z += bflo(u0.y); a0.w += bfhi(u0.y);
        }
        a0.x += a1.x + a2.x + a3.x;
        a0.y += a1.y + a2.y + a3.y;
        a0.z += a1.z + a2.z + a3.z;
        a0.w += a1.w + a2.w + a3.w;
        *(float4*)(H + (size_t)node * HID + j0) = a0;
    }
}

// ---------------------------------------------------------------------------
// Readout from pe directly: one block per bucket, 32 LDS float accumulators.
// out[node] = bf + sum of S[src] over the bucket's edges with dlow == node&31.
// ---------------------------------------------------------------------------
__global__ __launch_bounds__(256) void bucket_scalar(
    const uint_t* __restrict__ pe, const int* __restrict__ basea,
    const float* __restrict__ S, const float* __restrict__ bf,
    float* __restrict__ O, int n_nodes, int nbuck)
{
    __shared__ float acc[32];
    const int b = blockIdx.x;
    const int t = threadIdx.x;
    if (t < 32) acc[t] = 0.f;
    __syncthreads();
    const int start = basea[b * NBLK];
    const int end   = basea[(b + 1) * NBLK];
    for (int i = start + t; i < end; i += 256) {
        const uint_t w = pe[i];
        atomicAdd(&acc[(w >> 16) & 31], S[w & 0xFFFFu]);
    }
    __syncthreads();
    if (t < 32) {
        const int node = b * 32 + t;
        if (node < n_nodes) O[node] = bf[0] + acc[t];
    }
}

// ---------------------------------------------------------------------------
// Fallback atomic path (used only if workspace is too small for CSR)
// ---------------------------------------------------------------------------
__global__ __launch_bounds__(256) void scatter_vec(
    const ushort_t* __restrict__ T, const int* __restrict__ E,
    const int* __restrict__ flag, float* __restrict__ H,
    int n_edges, int n_nodes)
{
    const bool is64 = (flag[0] != 0);
    const int l32 = threadIdx.x & 31;
    const int j0  = l32 * 4;
    const int grp  = (int)((blockIdx.x * blockDim.x + threadIdx.x) >> 5);
    const int ngrp = (int)((gridDim.x * blockDim.x) >> 5);
    for (int e = grp; e < n_edges; e += ngrp) {
        const int src = load_idx(E, e, is64);
        const int dst = load_idx(E, n_edges + e, is64);
        if ((unsigned)src >= (unsigned)n_nodes || (unsigned)dst >= (unsigned)n_nodes) continue;
        const uint2 u = *(const uint2*)(T + (size_t)src * HID + j0);
        float* hp = H + (size_t)dst * HID + j0;
        unsafeAtomicAdd(hp + 0, bflo(u.x));
        unsafeAtomicAdd(hp + 1, bfhi(u.x));
        unsafeAtomicAdd(hp + 2, bflo(u.y));
        unsafeAtomicAdd(hp + 3, bfhi(u.y));
    }
}

__global__ __launch_bounds__(256) void scatter_scalar(
    const float* __restrict__ S, const int* __restrict__ E,
    const int* __restrict__ flag, float* __restrict__ O,
    int n_edges, int n_nodes)
{
    const bool is64 = (flag[0] != 0);
    const int t  = blockIdx.x * blockDim.x + threadIdx.x;
    const int nt = gridDim.x * blockDim.x;
    for (int e = t; e < n_edges; e += nt) {
        const int src = load_idx(E, e, is64);
        const int dst = load_idx(E, n_edges + e, is64);
        if ((unsigned)src >= (unsigned)n_nodes || (unsigned)dst >= (unsigned)n_nodes) continue;
        unsafeAtomicAdd(O + dst, S[src]);
    }
}

__global__ void init_out(float* __restrict__ O, const float* __restrict__ bf, int n) {
    int i = blockIdx.x * blockDim.x + threadIdx.x;
    if (i < n) O[i] = bf[0];
}

extern "C" void kernel_launch(void* const* d_in, const int* in_sizes, int n_in,
                              void* d_out, int out_size, void* d_ws, size_t ws_size,
                              hipStream_t stream) {
    const float* x  = (const float*)d_in[0];
    const int*   E  = (const int*)d_in[1];
    const float* W1 = (const float*)d_in[2];
    const float* b1 = (const float*)d_in[3];
    const float* W2 = (const float*)d_in[4];
    const float* b2 = (const float*)d_in[5];
    const float* Wf = (const float*)d_in[6];
    const float* bf = (const float*)d_in[7];
    float* out = (float*)d_out;

    const int n  = in_sizes[0] / HID;   // 50000 nodes
    const int ne = in_sizes[1] / 2;     // 800000 edges
    const int nbuck = (n + 31) / 32;    // 1563 buckets
    const int m     = nbuck * NBLK;     // partition counters

    const size_t featB = (size_t)n * HID * 4;
    char* ws = (char*)d_ws;
    int*      flag = (int*)ws;
    ushort_t* wt1  = (ushort_t*)(ws + 1024);            // 32 KB
    ushort_t* wt2  = (ushort_t*)(ws + 1024 + 32768);    // 32 KB
    ushort_t* t1   = (ushort_t*)(ws + 1024 + 65536);    // n*128 bf16 (in featB slot)
    float*    h1   = (float*)(ws + 1024 + 65536 + featB);
    char*     p    = ws + 1024 + 65536 + 2 * featB;
    uint_t* pe    = (uint_t*)p;                 p += (size_t)ne * 4;
    int*   ovf    = (int*)p;                    p += (size_t)ne * 4;
    int*   histT  = (int*)p;                    p += (size_t)m * 4;
    int*   basea  = (int*)p;                    p += (size_t)(m + 1) * 4;
    int*   bsum   = (int*)p;                    p += (size_t)NBLK * 4;
    const size_t needed = (size_t)(p - ws);
    float* s = (float*)(ws + 1024 + 65536);   // t1 dead after aggregation; reuse slot

    const int gemm_grid = (n + 63) / 64;

    prep_all<<<129, 256, 0, stream>>>(E, flag, W1, W2, wt1, wt2);

    // layer 1 per-node transform (bf16 out) via MFMA
    mlp_mfma<<<gemm_grid, 256, 0, stream>>>(x, wt1, b1, nullptr, t1, nullptr, n, 0);

    if (ws_size >= needed && n <= 65536 && nbuck <= MAXBUCK) {
        // ---- single cooperative launch: hist + scan + scatter ----
        int ne_v = ne, n_v = n, nbuck_v = nbuck;
        void* args[] = {(void*)&E, (void*)&histT, (void*)&basea, (void*)&bsum,
                        (void*)&pe, (void*)&ne_v, (void*)&n_v, (void*)&nbuck_v};
        (void)hipLaunchCooperativeKernel((const void*)coop_partition,
                                         dim3(NBLK), dim3(PTHREADS), args, 0, stream);

        // ---- fused bucket CSR + vector gather (writes H) ----
        bucket_gather<<<nbuck, 256, 0, stream>>>(pe, basea, t1, h1, ovf, n, nbuck);

        // layer 2 fused with readout: s[m] = relu(h1[m]@W2+b2) . Wf
        mlp_mfma<<<gemm_grid, 256, 0, stream>>>(h1, wt2, b2, Wf, nullptr, s, n, 1);

        // readout gather straight from pe
        bucket_scalar<<<nbuck, 256, 0, stream>>>(pe, basea, s, bf, out, n, nbuck);
    } else {
        // ---- fallback: atomic scatter path ----
        (void)hipMemsetAsync(h1, 0, featB, stream);
        scatter_vec<<<8192, 256, 0, stream>>>(t1, E, flag, h1, ne, n);
        mlp_mfma<<<gemm_grid, 256, 0, stream>>>(h1, wt2, b2, Wf, nullptr, s, n, 1);
        init_out<<<(n + 255) / 256, 256, 0, stream>>>(out, bf, n);
        scatter_scalar<<<2048, 256, 0, stream>>>(s, E, flag, out, ne, n);
    }
}

// Round 14
// 98.957 us; speedup vs baseline: 1.5260x; 1.5260x over previous
//
#include <hip/hip_runtime.h>

#define HID 128
#define NBLK 64          // partition chunks
#define PTHREADS 1024    // threads per partition/hist block
#define MAXBUCK 2048     // buckets of 32 dst nodes; supports n <= 65536
#define CAP 3072         // LDS capacity (edges) per bucket in bucket_gather

typedef unsigned short ushort_t;
typedef unsigned int uint_t;
typedef short bf16x8 __attribute__((ext_vector_type(8)));
typedef float f32x4 __attribute__((ext_vector_type(4)));

__device__ __forceinline__ float bflo(uint_t u) { return __uint_as_float(u << 16); }
__device__ __forceinline__ float bfhi(uint_t u) { return __uint_as_float(u & 0xFFFF0000u); }
__device__ __forceinline__ uint_t f2bf(float f) {
    uint_t x = __float_as_uint(f);
    return (x + 0x7FFFu + ((x >> 16) & 1u)) >> 16;   // RNE
}

__device__ __forceinline__ int load_idx(const int* __restrict__ E, int pos, bool is64) {
    return is64 ? E[2 * pos] : E[pos];
}

// ---------------------------------------------------------------------------
// prep_hist (one launch, 1024 thr/block):
//   blocks 0..31  : transpose W1/W2 -> bf16 Wt[col][k]
//   block  32     : detect int64 vs int32 edge layout -> flag
//   blocks 33..33+NBLK-1 : per-block LDS histogram of dst buckets (both-valid)
// Fallback mode launches only 33 blocks (no hist -> no ws histT writes).
// ---------------------------------------------------------------------------
__global__ __launch_bounds__(PTHREADS) void prep_hist(
    const int* __restrict__ E, int* __restrict__ flag,
    const float* __restrict__ W1, const float* __restrict__ W2,
    ushort_t* __restrict__ wt1, ushort_t* __restrict__ wt2,
    int* __restrict__ histT, int n_edges, int n_nodes, int nbuck)
{
    const int t = threadIdx.x;
    if (blockIdx.x < 32) {
        const int id = blockIdx.x * PTHREADS + t;        // 0..32767
        const float* W = (id < 16384) ? W1 : W2;
        ushort_t* O    = (id < 16384) ? wt1 : wt2;
        const int i   = id & 16383;
        const int col = i >> 7;
        const int k   = i & 127;
        O[col * 128 + k] = (ushort_t)f2bf(W[k * 128 + col]);
        return;
    }
    if (blockIdx.x == 32) {
        if (t < 64) {
            const int v = E[2 * t + 1] | E[2 * (t + 64) + 1];
            unsigned long long b = __ballot(v != 0);
            if (t == 0) flag[0] = (b == 0ull) ? 1 : 0;
        }
        return;
    }
    // histogram blocks
    __shared__ int h[MAXBUCK];
    __shared__ int s_is64;
    const int hb = blockIdx.x - 33;
    if (t < 64) {
        const int v = E[2 * t + 1] | E[2 * (t + 64) + 1];
        unsigned long long b = __ballot(v != 0);
        if (t == 0) s_is64 = (b == 0ull) ? 1 : 0;
    }
    for (int i = t; i < nbuck; i += PTHREADS) h[i] = 0;
    __syncthreads();
    const bool is64 = (s_is64 != 0);
    const int chunk = (n_edges + NBLK - 1) / NBLK;
    const int c0 = hb * chunk;
    const int c1 = min(c0 + chunk, n_edges);
    for (int e = c0 + t; e < c1; e += PTHREADS) {
        const int src = load_idx(E, e, is64);
        const int dst = load_idx(E, n_edges + e, is64);
        if ((unsigned)src < (unsigned)n_nodes && (unsigned)dst < (unsigned)n_nodes)
            atomicAdd(&h[dst >> 5], 1);
    }
    __syncthreads();
    for (int i = t; i < nbuck; i += PTHREADS)
        histT[i * NBLK + hb] = h[i];
}

// ---------------------------------------------------------------------------
// MFMA GEMM: T = relu(X @ W + B) using v_mfma_f32_16x16x32_bf16.
// Block = 256 thr = 4 waves; each wave owns 16 rows x 128 cols.
// Wt (transposed bf16 W) staged once into LDS with granule-XOR swizzle.
// No per-K barriers: LDS read-only after one stage barrier.
// C/D layout (verified): col=lane&15, row=(lane>>4)*4+reg.
// mode 0: write T rows (bf16). mode 1: fuse dot with Wf, write scalar S.
// ---------------------------------------------------------------------------
__global__ __launch_bounds__(256) void mlp_mfma(
    const float* __restrict__ X, const ushort_t* __restrict__ Wt,
    const float* __restrict__ Bv, const float* __restrict__ Wf,
    ushort_t* __restrict__ T, float* __restrict__ S, int n, int mode)
{
    __shared__ ushort_t Wl[HID * HID];   // 32 KB, swizzled

    {
        const uint4* src = (const uint4*)Wt;
        for (int o = threadIdx.x; o < 2048; o += 256) {
            const uint4 v = src[o];
            const int col = o >> 4;
            const int g   = o & 15;
            const int gs  = g ^ (col & 7);
            *(uint4*)(Wl + col * HID + gs * 8) = v;
        }
    }
    __syncthreads();

    const int l  = threadIdx.x & 63;
    const int wv = threadIdx.x >> 6;
    const int rowbase = blockIdx.x * 64 + wv * 16;
    const int lr = l & 15;
    const int lg = l >> 4;

    f32x4 acc[8];
#pragma unroll
    for (int ct = 0; ct < 8; ++ct) acc[ct] = (f32x4){0.f, 0.f, 0.f, 0.f};

    const int arow = rowbase + lr;
    const bool rok = (arow < n);

    for (int kk = 0; kk < 4; ++kk) {
        bf16x8 a;
        if (rok) {
            const float* xp = X + (size_t)arow * HID + kk * 32 + lg * 8;
            const float4 x0 = *(const float4*)xp;
            const float4 x1 = *(const float4*)(xp + 4);
            a[0] = (short)f2bf(x0.x); a[1] = (short)f2bf(x0.y);
            a[2] = (short)f2bf(x0.z); a[3] = (short)f2bf(x0.w);
            a[4] = (short)f2bf(x1.x); a[5] = (short)f2bf(x1.y);
            a[6] = (short)f2bf(x1.z); a[7] = (short)f2bf(x1.w);
        } else {
            a = (bf16x8){0, 0, 0, 0, 0, 0, 0, 0};
        }
#pragma unroll
        for (int ct = 0; ct < 8; ++ct) {
            const int col = ct * 16 + lr;
            const int g   = kk * 4 + lg;
            const int gs  = g ^ (col & 7);
            const bf16x8 b = *(const bf16x8*)(Wl + col * HID + gs * 8);
            acc[ct] = __builtin_amdgcn_mfma_f32_16x16x32_bf16(a, b, acc[ct], 0, 0, 0);
        }
    }

    if (mode == 0) {
#pragma unroll
        for (int ct = 0; ct < 8; ++ct) {
            const float bvc = Bv[ct * 16 + lr];
#pragma unroll
            for (int i = 0; i < 4; ++i) {
                const int r = rowbase + lg * 4 + i;
                if (r < n) {
                    const float v = fmaxf(acc[ct][i] + bvc, 0.f);
                    T[(size_t)r * HID + ct * 16 + lr] = (ushort_t)f2bf(v);
                }
            }
        }
    } else {
        float p0 = 0.f, p1 = 0.f, p2 = 0.f, p3 = 0.f;
#pragma unroll
        for (int ct = 0; ct < 8; ++ct) {
            const float bvc = Bv[ct * 16 + lr];
            const float wfc = Wf[ct * 16 + lr];
            p0 += fmaxf(acc[ct][0] + bvc, 0.f) * wfc;
            p1 += fmaxf(acc[ct][1] + bvc, 0.f) * wfc;
            p2 += fmaxf(acc[ct][2] + bvc, 0.f) * wfc;
            p3 += fmaxf(acc[ct][3] + bvc, 0.f) * wfc;
        }
#pragma unroll
        for (int m = 1; m <= 8; m <<= 1) {
            p0 += __shfl_xor(p0, m);
            p1 += __shfl_xor(p1, m);
            p2 += __shfl_xor(p2, m);
            p3 += __shfl_xor(p3, m);
        }
        if (lr == 0) {
            const int r = rowbase + lg * 4;
            if (r + 0 < n) S[r + 0] = p0;
            if (r + 1 < n) S[r + 1] = p1;
            if (r + 2 < n) S[r + 2] = p2;
            if (r + 3 < n) S[r + 3] = p3;
        }
    }
}

// ---------------------------------------------------------------------------
// Scan stage 1: per-256-chunk exclusive scan; block sums out.
// ---------------------------------------------------------------------------
__global__ __launch_bounds__(256) void scang_blk(
    const int* __restrict__ A, int* __restrict__ out,
    int* __restrict__ bsum, int m)
{
    __shared__ int sd[256];
    const int t = threadIdx.x;
    const int i = blockIdx.x * 256 + t;
    const int v = (i < m) ? A[i] : 0;
    sd[t] = v;
    __syncthreads();
    for (int d = 1; d < 256; d <<= 1) {
        const int u = (t >= d) ? sd[t - d] : 0;
        __syncthreads();
        sd[t] += u;
        __syncthreads();
    }
    if (i < m) out[i] = sd[t] - v;
    if (t == 255) bsum[blockIdx.x] = sd[255];
}

// ---------------------------------------------------------------------------
// Scan stage 2 (fused top-scan + add): block b sums bsum[0..b) locally and
// adds; block 0 also writes the grand total to out[m].
// ---------------------------------------------------------------------------
__global__ __launch_bounds__(256) void scang_add2(
    int* __restrict__ out, const int* __restrict__ bsum, int nb, int m)
{
    __shared__ int red[256];
    const int t = threadIdx.x;
    const int b = blockIdx.x;
    int partial = 0, total = 0;
    for (int i = t; i < nb; i += 256) {
        const int v = bsum[i];
        if (i < b) partial += v;
        total += v;
    }
    red[t] = partial;
    __syncthreads();
    for (int d = 128; d; d >>= 1) {
        if (t < d) red[t] += red[t + d];
        __syncthreads();
    }
    const int add = red[0];
    const int i = b * 256 + t;
    if (i < m) out[i] += add;
    if (b == 0) {
        __syncthreads();
        red[t] = total;
        __syncthreads();
        for (int d = 128; d; d >>= 1) {
            if (t < d) red[t] += red[t + d];
            __syncthreads();
        }
        if (t == 0) out[m] = red[0];
    }
}

// ---------------------------------------------------------------------------
// Partition scatter: packed (src | dlow<<16) into per-(block,bucket)
// EXCLUSIVE ranges; positions from LDS counters.
// ---------------------------------------------------------------------------
__global__ __launch_bounds__(PTHREADS) void part_scatter(
    const int* __restrict__ E, const int* __restrict__ flag,
    const int* __restrict__ basea, uint_t* __restrict__ pe,
    int n_edges, int n_nodes, int nbuck)
{
    __shared__ int cur[MAXBUCK];
    for (int i = threadIdx.x; i < nbuck; i += PTHREADS)
        cur[i] = basea[i * NBLK + blockIdx.x];
    __syncthreads();
    const bool is64 = (flag[0] != 0);
    const int chunk = (n_edges + NBLK - 1) / NBLK;
    const int c0 = blockIdx.x * chunk;
    const int c1 = min(c0 + chunk, n_edges);
    for (int e = c0 + (int)threadIdx.x; e < c1; e += PTHREADS) {
        const int src = load_idx(E, e, is64);
        const int dst = load_idx(E, n_edges + e, is64);
        if ((unsigned)src >= (unsigned)n_nodes || (unsigned)dst >= (unsigned)n_nodes) continue;
        const int p = atomicAdd(&cur[dst >> 5], 1);
        pe[p] = (uint_t)src | ((uint_t)(dst & 31) << 16);
    }
}

// ---------------------------------------------------------------------------
// Fused bucket CSR + vector gather: one 256-thread block per bucket of 32
// dst nodes. Per-dst sorted src list built in LDS; 8 x 32-lane groups gather
// T rows via LDS-resident indices. No global index round-trip.
// ---------------------------------------------------------------------------
__global__ __launch_bounds__(256) void bucket_gather(
    const uint_t* __restrict__ pe, const int* __restrict__ basea,
    const ushort_t* __restrict__ T, float* __restrict__ H,
    int* __restrict__ ovf, int n_nodes, int nbuck)
{
    __shared__ int sid[CAP];
    __shared__ int cnt[32];
    __shared__ int cur[32];
    __shared__ int loff[32];
    const int b = blockIdx.x;
    const int t = threadIdx.x;
    const int start = basea[b * NBLK];
    const int end   = basea[(b + 1) * NBLK];
    const int m     = end - start;

    if (t < 32) cnt[t] = 0;
    __syncthreads();
    for (int i = start + t; i < end; i += 256)
        atomicAdd(&cnt[(pe[i] >> 16) & 31], 1);
    __syncthreads();
    if (t < 32) {
        const int v = cnt[t];
        int s = v;
        for (int d = 1; d < 32; d <<= 1) {
            const int u = __shfl_up(s, d, 64);
            if (t >= d) s += u;
        }
        const int excl = s - v;
        loff[t] = excl;
        cur[t]  = excl;
    }
    __syncthreads();

    const bool fits = (m <= CAP);
    for (int i = start + t; i < end; i += 256) {
        const uint_t w = pe[i];
        const int p = atomicAdd(&cur[(w >> 16) & 31], 1);
        const int s = (int)(w & 0xFFFFu);
        if (fits) sid[p] = s;
        else      ovf[start + p] = s;
    }
    __syncthreads();

    const int grp = t >> 5;
    const int l32 = t & 31;
    const int j0  = l32 * 4;
    for (int nd = grp; nd < 32; nd += 8) {
        const int node = b * 32 + nd;
        if (node >= n_nodes) break;
        const int k0 = loff[nd];
        const int k1 = (nd < 31) ? loff[nd + 1] : m;
        float4 a0 = {0.f, 0.f, 0.f, 0.f};
        float4 a1 = {0.f, 0.f, 0.f, 0.f};
        float4 a2 = {0.f, 0.f, 0.f, 0.f};
        float4 a3 = {0.f, 0.f, 0.f, 0.f};
        int k = k0;
        for (; k + 4 <= k1; k += 4) {
            const int s0 = fits ? sid[k + 0] : ovf[start + k + 0];
            const int s1 = fits ? sid[k + 1] : ovf[start + k + 1];
            const int s2 = fits ? sid[k + 2] : ovf[start + k + 2];
            const int s3 = fits ? sid[k + 3] : ovf[start + k + 3];
            const uint2 u0 = *(const uint2*)(T + (size_t)s0 * HID + j0);
            const uint2 u1 = *(const uint2*)(T + (size_t)s1 * HID + j0);
            const uint2 u2 = *(const uint2*)(T + (size_t)s2 * HID + j0);
            const uint2 u3 = *(const uint2*)(T + (size_t)s3 * HID + j0);
            a0.x += bflo(u0.x); a0.y += bfhi(u0.x);
            a0.z += bflo(u0.y); a0.w += bfhi(u0.y);
            a1.x += bflo(u1.x); a1.y += bfhi(u1.x);
            a1.z += bflo(u1.y); a1.w += bfhi(u1.y);
            a2.x += bflo(u2.x); a2.y += bfhi(u2.x);
            a2.z += bflo(u2.y); a2.w += bfhi(u2.y);
            a3.x += bflo(u3.x); a3.y += bfhi(u3.x);
            a3.z += bflo(u3.y); a3.w += bfhi(u3.y);
        }
        for (; k < k1; ++k) {
            const int s0 = fits ? sid[k] : ovf[start + k];
            const uint2 u0 = *(const uint2*)(T + (size_t)s0 * HID + j0);
            a0.x += bflo(u0.x); a0.y += bfhi(u0.x);
            a0.z += bflo(u0.y); a0.w += bfhi(u0.y);
        }
        a0.x += a1.x + a2.x + a3.x;
        a0.y += a1.y + a2.y + a3.y;
        a0.z += a1.z + a2.z + a3.z;
        a0.w += a1.w + a2.w + a3.w;
        *(float4*)(H + (size_t)node * HID + j0) = a0;
    }
}

// ---------------------------------------------------------------------------
// Readout from pe directly: one block per bucket, 32 LDS float accumulators.
// ---------------------------------------------------------------------------
__global__ __launch_bounds__(256) void bucket_scalar(
    const uint_t* __restrict__ pe, const int* __restrict__ basea,
    const float* __restrict__ S, const float* __restrict__ bf,
    float* __restrict__ O, int n_nodes, int nbuck)
{
    __shared__ float acc[32];
    const int b = blockIdx.x;
    const int t = threadIdx.x;
    if (t < 32) acc[t] = 0.f;
    __syncthreads();
    const int start = basea[b * NBLK];
    const int end   = basea[(b + 1) * NBLK];
    for (int i = start + t; i < end; i += 256) {
        const uint_t w = pe[i];
        atomicAdd(&acc[(w >> 16) & 31], S[w & 0xFFFFu]);
    }
    __syncthreads();
    if (t < 32) {
        const int node = b * 32 + t;
        if (node < n_nodes) O[node] = bf[0] + acc[t];
    }
}

// ---------------------------------------------------------------------------
// Fallback atomic path (used only if workspace is too small for CSR)
// ---------------------------------------------------------------------------
__global__ __launch_bounds__(256) void scatter_vec(
    const ushort_t* __restrict__ T, const int* __restrict__ E,
    const int* __restrict__ flag, float* __restrict__ H,
    int n_edges, int n_nodes)
{
    const bool is64 = (flag[0] != 0);
    const int l32 = threadIdx.x & 31;
    const int j0  = l32 * 4;
    const int grp  = (int)((blockIdx.x * blockDim.x + threadIdx.x) >> 5);
    const int ngrp = (int)((gridDim.x * blockDim.x) >> 5);
    for (int e = grp; e < n_edges; e += ngrp) {
        const int src = load_idx(E, e, is64);
        const int dst = load_idx(E, n_edges + e, is64);
        if ((unsigned)src >= (unsigned)n_nodes || (unsigned)dst >= (unsigned)n_nodes) continue;
        const uint2 u = *(const uint2*)(T + (size_t)src * HID + j0);
        float* hp = H + (size_t)dst * HID + j0;
        unsafeAtomicAdd(hp + 0, bflo(u.x));
        unsafeAtomicAdd(hp + 1, bfhi(u.x));
        unsafeAtomicAdd(hp + 2, bflo(u.y));
        unsafeAtomicAdd(hp + 3, bfhi(u.y));
    }
}

__global__ __launch_bounds__(256) void scatter_scalar(
    const float* __restrict__ S, const int* __restrict__ E,
    const int* __restrict__ flag, float* __restrict__ O,
    int n_edges, int n_nodes)
{
    const bool is64 = (flag[0] != 0);
    const int t  = blockIdx.x * blockDim.x + threadIdx.x;
    const int nt = gridDim.x * blockDim.x;
    for (int e = t; e < n_edges; e += nt) {
        const int src = load_idx(E, e, is64);
        const int dst = load_idx(E, n_edges + e, is64);
        if ((unsigned)src >= (unsigned)n_nodes || (unsigned)dst >= (unsigned)n_nodes) continue;
        unsafeAtomicAdd(O + dst, S[src]);
    }
}

__global__ void init_out(float* __restrict__ O, const float* __restrict__ bf, int n) {
    int i = blockIdx.x * blockDim.x + threadIdx.x;
    if (i < n) O[i] = bf[0];
}

extern "C" void kernel_launch(void* const* d_in, const int* in_sizes, int n_in,
                              void* d_out, int out_size, void* d_ws, size_t ws_size,
                              hipStream_t stream) {
    const float* x  = (const float*)d_in[0];
    const int*   E  = (const int*)d_in[1];
    const float* W1 = (const float*)d_in[2];
    const float* b1 = (const float*)d_in[3];
    const float* W2 = (const float*)d_in[4];
    const float* b2 = (const float*)d_in[5];
    const float* Wf = (const float*)d_in[6];
    const float* bf = (const float*)d_in[7];
    float* out = (float*)d_out;

    const int n  = in_sizes[0] / HID;   // 50000 nodes
    const int ne = in_sizes[1] / 2;     // 800000 edges
    const int nbuck  = (n + 31) / 32;   // 1563 buckets
    const int m      = nbuck * NBLK;    // 100,032 partition counters
    const int nbscan = (m + 255) / 256; // 391 scan blocks

    const size_t featB = (size_t)n * HID * 4;
    char* ws = (char*)d_ws;
    int*      flag = (int*)ws;
    ushort_t* wt1  = (ushort_t*)(ws + 1024);            // 32 KB
    ushort_t* wt2  = (ushort_t*)(ws + 1024 + 32768);    // 32 KB
    ushort_t* t1   = (ushort_t*)(ws + 1024 + 65536);    // n*128 bf16 (in featB slot)
    float*    h1   = (float*)(ws + 1024 + 65536 + featB);
    char*     p    = ws + 1024 + 65536 + 2 * featB;
    uint_t* pe    = (uint_t*)p;                 p += (size_t)ne * 4;
    int*   ovf    = (int*)p;                    p += (size_t)ne * 4;
    int*   histT  = (int*)p;                    p += (size_t)m * 4;
    int*   basea  = (int*)p;                    p += (size_t)(m + 1) * 4;
    int*   bsum   = (int*)p;                    p += (size_t)nbscan * 4;
    const size_t needed = (size_t)(p - ws);
    float* s = (float*)(ws + 1024 + 65536);   // t1 dead after aggregation; reuse slot

    const int gemm_grid = (n + 63) / 64;
    const bool csr_ok = (ws_size >= needed && n <= 65536 && nbuck <= MAXBUCK);

    // one launch: W transpose + is64 detect (+ dst histogram when CSR path)
    prep_hist<<<csr_ok ? (33 + NBLK) : 33, PTHREADS, 0, stream>>>(
        E, flag, W1, W2, wt1, wt2, histT, ne, n, nbuck);

    // layer 1 per-node transform (bf16 out) via MFMA
    mlp_mfma<<<gemm_grid, 256, 0, stream>>>(x, wt1, b1, nullptr, t1, nullptr, n, 0);

    if (csr_ok) {
        scang_blk<<<nbscan, 256, 0, stream>>>(histT, basea, bsum, m);
        scang_add2<<<nbscan, 256, 0, stream>>>(basea, bsum, nbscan, m);
        part_scatter<<<NBLK, PTHREADS, 0, stream>>>(E, flag, basea, pe, ne, n, nbuck);

        // fused bucket CSR + vector gather (writes H)
        bucket_gather<<<nbuck, 256, 0, stream>>>(pe, basea, t1, h1, ovf, n, nbuck);

        // layer 2 fused with readout: s[m] = relu(h1[m]@W2+b2) . Wf
        mlp_mfma<<<gemm_grid, 256, 0, stream>>>(h1, wt2, b2, Wf, nullptr, s, n, 1);

        // readout gather straight from pe
        bucket_scalar<<<nbuck, 256, 0, stream>>>(pe, basea, s, bf, out, n, nbuck);
    } else {
        // fallback: atomic scatter path
        (void)hipMemsetAsync(h1, 0, featB, stream);
        scatter_vec<<<8192, 256, 0, stream>>>(t1, E, flag, h1, ne, n);
        mlp_mfma<<<gemm_grid, 256, 0, stream>>>(h1, wt2, b2, Wf, nullptr, s, n, 1);
        init_out<<<(n + 255) / 256, 256, 0, stream>>>(out, bf, n);
        scatter_scalar<<<2048, 256, 0, stream>>>(s, E, flag, out, ne, n);
    }
}